// Round 7
// baseline (535.996 us; speedup 1.0000x reference)
//
#include <hip/hip_runtime.h>

typedef unsigned short ushort_t;
typedef short bf16x8 __attribute__((ext_vector_type(8)));
typedef float f32x4 __attribute__((ext_vector_type(4)));
typedef float f32x16 __attribute__((ext_vector_type(16)));

#define S_LEN 4096
#define DIM   1536
#define NH    12
#define HD    128
#define KVSPLIT 4
#define ROWS (NH * S_LEN)
#define OPSPLIT_ELEMS ((size_t)ROWS * HD)

__device__ __forceinline__ float bf2f(ushort_t h) {
  union { unsigned u; float f; } v; v.u = ((unsigned)h) << 16; return v.f;
}
__device__ __forceinline__ ushort_t f2bf(float f) {
  union { float f; unsigned u; } v; v.f = f;
  return (ushort_t)((v.u + 0x7FFFu + ((v.u >> 16) & 1u)) >> 16);
}
__device__ __forceinline__ unsigned cvtpk(float lo, float hi_) {
  unsigned r; asm("v_cvt_pk_bf16_f32 %0, %1, %2" : "=v"(r) : "v"(lo), "v"(hi_)); return r;
}

// async global->LDS, 16B per lane; LDS dest must be uniform base + lane*16
#define GLD16(gp, lp) __builtin_amdgcn_global_load_lds( \
    (const __attribute__((address_space(1))) unsigned int*)(gp), \
    (__attribute__((address_space(3))) unsigned int*)(lp), 16, 0, 0)

// ---------------------------------------------------------------- convert
__global__ void __launch_bounds__(256) cvt_bf16(const float* __restrict__ in,
                                                ushort_t* __restrict__ out, int n4) {
  int i = blockIdx.x * 256 + threadIdx.x;
  int stride = gridDim.x * 256;
  for (; i < n4; i += stride) {
    float4 v = ((const float4*)in)[i];
    ushort4 o;
    o.x = f2bf(v.x); o.y = f2bf(v.y); o.z = f2bf(v.z); o.w = f2bf(v.w);
    ((ushort4*)out)[i] = o;
  }
}

// ------------------------------------------------- GEMM: C = A * W^T + bias
template <int F32OUT>
__global__ void __launch_bounds__(256) gemm_bt(
    const ushort_t* __restrict__ A, const ushort_t* __restrict__ Wbase,
    const float* __restrict__ b0, const float* __restrict__ b1, const float* __restrict__ b2,
    void* __restrict__ Cbase_v, int M, int N, int K)
{
  const int z = blockIdx.z;
  const ushort_t* W = Wbase + (size_t)z * N * K;
  const float* bias = (z == 0) ? b0 : (z == 1) ? b1 : b2;

  const int n0 = blockIdx.x * 128;
  const int m0 = blockIdx.y * 128;
  const int t = threadIdx.x;
  const int lane = t & 63;
  const int w = t >> 6;
  const int wr = w >> 1, wc = w & 1;
  const int mp = lane & 15, g = lane >> 4;

  __shared__ __attribute__((aligned(16))) ushort_t As[128 * 64];
  __shared__ __attribute__((aligned(16))) ushort_t Bs[128 * 64];

  f32x4 acc[4][4];
  f32x4 zero = {0.f, 0.f, 0.f, 0.f};
#pragma unroll
  for (int i = 0; i < 4; ++i)
#pragma unroll
    for (int j = 0; j < 4; ++j) acc[i][j] = zero;

  for (int kt = 0; kt < K; kt += 64) {
    __syncthreads();
#pragma unroll
    for (int i = 0; i < 4; ++i) {
      int p = i * 256 + t;
      int r = p >> 3, sl = p & 7;
      int sg = sl ^ (r & 7);
      GLD16(A + (size_t)(m0 + r) * K + kt + sg * 8, As + p * 8);
      GLD16(W + (size_t)(n0 + r) * K + kt + sg * 8, Bs + p * 8);
    }
    __syncthreads();
#pragma unroll
    for (int kk = 0; kk < 2; ++kk) {
      bf16x8 af[4], bfr[4];
#pragma unroll
      for (int mi = 0; mi < 4; ++mi) {
        int row = wr * 64 + mi * 16 + mp;
        int ch = (g + 4 * kk) ^ (row & 7);
        af[mi] = *(const bf16x8*)(As + row * 64 + ch * 8);
      }
#pragma unroll
      for (int ni = 0; ni < 4; ++ni) {
        int row = wc * 64 + ni * 16 + mp;
        int ch = (g + 4 * kk) ^ (row & 7);
        bfr[ni] = *(const bf16x8*)(Bs + row * 64 + ch * 8);
      }
#pragma unroll
      for (int mi = 0; mi < 4; ++mi)
#pragma unroll
        for (int ni = 0; ni < 4; ++ni)
          acc[mi][ni] = __builtin_amdgcn_mfma_f32_16x16x32_bf16(af[mi], bfr[ni], acc[mi][ni], 0, 0, 0);
    }
  }
#pragma unroll
  for (int ni = 0; ni < 4; ++ni) {
    int n = n0 + wc * 64 + ni * 16 + mp;
    float bv = bias[n];
#pragma unroll
    for (int mi = 0; mi < 4; ++mi) {
      int mbase = m0 + wr * 64 + mi * 16 + g * 4;
#pragma unroll
      for (int j = 0; j < 4; ++j) {
        if constexpr (F32OUT) {
          ((float*)Cbase_v)[(size_t)z * M * N + (size_t)(mbase + j) * N + n] =
              acc[mi][ni][j] + bv;
        } else {
          ((ushort_t*)Cbase_v)[(size_t)z * M * N + (size_t)(mbase + j) * N + n] =
              f2bf(acc[mi][ni][j] + bv);
        }
      }
    }
  }
}

// ------------------------------------- epilogue: RMSNorm + RoPE + relayout
__global__ void __launch_bounds__(256) epi_qkv(
    const ushort_t* __restrict__ raw,
    const float* __restrict__ gq, const float* __restrict__ gk,
    const float* __restrict__ fcos, const float* __restrict__ fsin,
    ushort_t* __restrict__ Qh, ushort_t* __restrict__ Kh, ushort_t* __restrict__ Vh)
{
  const int s = blockIdx.x;
  const int t = threadIdx.x;
  const ushort_t* rq = raw + (size_t)s * DIM;
  const ushort_t* rk = raw + (size_t)S_LEN * DIM + (size_t)s * DIM;
  const ushort_t* rv = raw + 2 * (size_t)S_LEN * DIM + (size_t)s * DIM;

  float sq = 0.f, sk = 0.f;
#pragma unroll
  for (int i = 0; i < 6; ++i) {
    int e = t + 256 * i;
    float a = bf2f(rq[e]); sq += a * a;
    float b = bf2f(rk[e]); sk += b * b;
  }
  for (int off = 1; off < 64; off <<= 1) {
    sq += __shfl_xor(sq, off, 64);
    sk += __shfl_xor(sk, off, 64);
  }
  __shared__ float red[2][4];
  int w = t >> 6;
  if ((t & 63) == 0) { red[0][w] = sq; red[1][w] = sk; }
  __syncthreads();
  sq = red[0][0] + red[0][1] + red[0][2] + red[0][3];
  sk = red[1][0] + red[1][1] + red[1][2] + red[1][3];
  float invq = rsqrtf(sq * (1.f / 1536.f) + 1e-6f);
  float invk = rsqrtf(sk * (1.f / 1536.f) + 1e-6f);

  const float qscale = 0.12752004708465604f;  // log2(e)/sqrt(128)
#pragma unroll
  for (int i = 0; i < 3; ++i) {
    int p = t + 256 * i;
    int hh = p >> 6, d = p & 63;
    int e1 = hh * 128 + d, e2 = e1 + 64;
    float c1 = fcos[s * 128 + d],      s1 = fsin[s * 128 + d];
    float c2 = fcos[s * 128 + d + 64], s2 = fsin[s * 128 + d + 64];
    float q1 = bf2f(rq[e1]) * invq * gq[e1];
    float q2 = bf2f(rq[e2]) * invq * gq[e2];
    float k1 = bf2f(rk[e1]) * invk * gk[e1];
    float k2 = bf2f(rk[e2]) * invk * gk[e2];
    size_t ob = ((size_t)hh * S_LEN + s) * 128;
    Qh[ob + d]      = f2bf((q1 * c1 - q2 * s1) * qscale);
    Qh[ob + d + 64] = f2bf((q2 * c2 + q1 * s2) * qscale);
    Kh[ob + d]      = f2bf(k1 * c1 - k2 * s1);
    Kh[ob + d + 64] = f2bf(k2 * c2 + k1 * s2);
  }
#pragma unroll
  for (int i = 0; i < 6; ++i) {
    int e = t + 256 * i;
    int hh = e >> 7, d = e & 127;
    Vh[((size_t)hh * S_LEN + s) * 128 + d] = rv[e];
  }
}

// ----------------------------------------------- V -> V^T per head (tiled)
__global__ void __launch_bounds__(256) transpose_v(const ushort_t* __restrict__ Vh,
                                                   ushort_t* __restrict__ VT) {
  const int st = blockIdx.x * 64;
  const int dt = blockIdx.y * 64;
  const int h = blockIdx.z;
  __shared__ ushort_t tile[64][65];
  const int t = threadIdx.x;
#pragma unroll
  for (int i = 0; i < 2; ++i) {
    int p = i * 256 + t;
    int r = p >> 3, c = (p & 7) * 8;
    bf16x8 v = *(const bf16x8*)(Vh + ((size_t)h * S_LEN + st + r) * 128 + dt + c);
#pragma unroll
    for (int j = 0; j < 8; ++j) tile[r][c + j] = ((ushort_t*)&v)[j];
  }
  __syncthreads();
#pragma unroll
  for (int i = 0; i < 2; ++i) {
    int p = i * 256 + t;
    int r = p >> 3, c = (p & 7) * 8;
    ushort_t tmp[8];
#pragma unroll
    for (int j = 0; j < 8; ++j) tmp[j] = tile[c + j][r];
    *(bf16x8*)(VT + ((size_t)h * 128 + dt + r) * S_LEN + st + c) = *(bf16x8*)tmp;
  }
}

// -------------------------------- shared pieces of the two attn variants
__device__ __forceinline__ void stage_kv(const ushort_t* __restrict__ Kg,
                                         const ushort_t* __restrict__ Vg,
                                         ushort_t* KsB, ushort_t* VsB, int t) {
#pragma unroll
  for (int i = 0; i < 8; ++i) {        // K tile: 64 rows x 16 chunks
    int p = i * 128 + t;
    int r = p >> 4, sl = p & 15;
    int sg = sl ^ (r & 7);
    GLD16(Kg + (size_t)r * 128 + sg * 8, KsB + p * 8);
  }
#pragma unroll
  for (int i = 0; i < 8; ++i) {        // V^T tile: 128 rows x 8 chunks
    int p = i * 128 + t;
    int r = p >> 3, sl = p & 7;
    int sg = sl ^ (r & 7);
    GLD16(Vg + (size_t)r * S_LEN + sg * 8, VsB + p * 8);
  }
}

struct AttnState {
  f32x16 oacc[4];
  float mrun, lrun;
};

// compute one 64-KV tile from LDS buffers (swapped QK^T + in-reg softmax + PV)
__device__ __forceinline__ void attn_tile(const ushort_t* KsB, const ushort_t* VsB,
                                          const bf16x8* qf, AttnState& st_,
                                          int ql, int hi) {
  f32x16 sa0, sa1;
#pragma unroll
  for (int r = 0; r < 16; ++r) { sa0[r] = 0.f; sa1[r] = 0.f; }
  __builtin_amdgcn_s_setprio(1);
#pragma unroll
  for (int s = 0; s < 8; ++s) {
    int ck = (2 * s + hi) ^ (ql & 7);
    bf16x8 k0 = *(const bf16x8*)(KsB + ql * 128 + ck * 8);
    bf16x8 k1 = *(const bf16x8*)(KsB + (32 + ql) * 128 + ck * 8);
    sa0 = __builtin_amdgcn_mfma_f32_32x32x16_bf16(k0, qf[s], sa0, 0, 0, 0);
    sa1 = __builtin_amdgcn_mfma_f32_32x32x16_bf16(k1, qf[s], sa1, 0, 0, 0);
  }
  __builtin_amdgcn_s_setprio(0);

  float mt[8];
#pragma unroll
  for (int r = 0; r < 8; ++r)
    mt[r] = fmaxf(fmaxf(sa0[r], sa0[r + 8]), fmaxf(sa1[r], sa1[r + 8]));
#pragma unroll
  for (int off = 4; off > 0; off >>= 1)
#pragma unroll
    for (int r = 0; r < 8; ++r)
      if (r < off) mt[r] = fmaxf(mt[r], mt[r + off]);
  float mx = fmaxf(mt[0], __shfl_xor(mt[0], 32));

  if (__any(mx - st_.mrun > 11.0f)) {
    float nm = fmaxf(st_.mrun, mx);
    float sc = exp2f(st_.mrun - nm);
    st_.mrun = nm;
    st_.lrun *= sc;
#pragma unroll
    for (int dt = 0; dt < 4; ++dt)
#pragma unroll
      for (int r = 0; r < 16; ++r) st_.oacc[dt][r] *= sc;
  }

  float rt[8];
#pragma unroll
  for (int r = 0; r < 16; ++r) {
    sa0[r] = exp2f(sa0[r] - st_.mrun);
    sa1[r] = exp2f(sa1[r] - st_.mrun);
  }
#pragma unroll
  for (int r = 0; r < 8; ++r) rt[r] = (sa0[r] + sa0[r + 8]) + (sa1[r] + sa1[r + 8]);
#pragma unroll
  for (int off = 4; off > 0; off >>= 1)
#pragma unroll
    for (int r = 0; r < 8; ++r)
      if (r < off) rt[r] += rt[r + off];
  st_.lrun += rt[0] + __shfl_xor(rt[0], 32);

  unsigned pw0[8], pw1[8];
#pragma unroll
  for (int a = 0; a < 4; ++a) {
    pw0[2 * a]     = cvtpk(sa0[4 * a], sa0[4 * a + 1]);
    pw0[2 * a + 1] = cvtpk(sa0[4 * a + 2], sa0[4 * a + 3]);
    pw1[2 * a]     = cvtpk(sa1[4 * a], sa1[4 * a + 1]);
    pw1[2 * a + 1] = cvtpk(sa1[4 * a + 2], sa1[4 * a + 3]);
  }

#pragma unroll
  for (int sx = 0; sx < 2; ++sx) {
#pragma unroll
    for (int ks = 0; ks < 2; ++ks) {
      unsigned q0w0 = sx ? pw1[4 * ks + 0] : pw0[4 * ks + 0];
      unsigned q0w1 = sx ? pw1[4 * ks + 1] : pw0[4 * ks + 1];
      unsigned q1w0 = sx ? pw1[4 * ks + 2] : pw0[4 * ks + 2];
      unsigned q1w1 = sx ? pw1[4 * ks + 3] : pw0[4 * ks + 3];
      unsigned sw0 = hi ? q0w0 : q1w0;
      unsigned sw1 = hi ? q0w1 : q1w1;
      unsigned rv0 = (unsigned)__shfl_xor((int)sw0, 32);
      unsigned rv1 = (unsigned)__shfl_xor((int)sw1, 32);
      union { unsigned u[4]; bf16x8 v; } fw;
      fw.u[0] = hi ? rv0 : q0w0;
      fw.u[1] = hi ? rv1 : q0w1;
      fw.u[2] = hi ? q1w0 : rv0;
      fw.u[3] = hi ? q1w1 : rv1;
      __builtin_amdgcn_s_setprio(1);
#pragma unroll
      for (int dt = 0; dt < 4; ++dt) {
        int d = 32 * dt + ql;
        int cv = (4 * sx + 2 * ks + hi) ^ (ql & 7);
        bf16x8 va = *(const bf16x8*)(VsB + d * 64 + cv * 8);
        st_.oacc[dt] = __builtin_amdgcn_mfma_f32_32x32x16_bf16(va, fw.v, st_.oacc[dt], 0, 0, 0);
      }
      __builtin_amdgcn_s_setprio(0);
    }
  }
}

__device__ __forceinline__ void attn_epilogue(AttnState& st_, int z, int row, int hi,
                                              ushort_t* __restrict__ opraw,
                                              ushort_t* __restrict__ opxb,
                                              float* __restrict__ mlbuf) {
  ushort_t* Op = (z < 3) ? (opraw + (size_t)z * OPSPLIT_ELEMS) : opxb;
  float inv = 1.f / st_.lrun;
#pragma unroll
  for (int dt = 0; dt < 4; ++dt) {
#pragma unroll
    for (int c = 0; c < 4; ++c) {
      float f0 = st_.oacc[dt][4 * c + 0] * inv, f1 = st_.oacc[dt][4 * c + 1] * inv;
      float f2 = st_.oacc[dt][4 * c + 2] * inv, f3 = st_.oacc[dt][4 * c + 3] * inv;
      uint2 u;
      u.x = cvtpk(f0, f1);
      u.y = cvtpk(f2, f3);
      *(uint2*)(Op + (size_t)row * 128 + 32 * dt + 8 * c + 4 * hi) = u;
    }
  }
  if (hi == 0) {
    mlbuf[2 * ((size_t)z * ROWS + row)]     = st_.mrun;
    mlbuf[2 * ((size_t)z * ROWS + row) + 1] = st_.lrun;
  }
}

// ------------------------- V0: serial stage/compute (round-6 structure)
__global__ void __launch_bounds__(128) attn32(
    const ushort_t* __restrict__ Qh, const ushort_t* __restrict__ Kh,
    const ushort_t* __restrict__ VT,
    ushort_t* __restrict__ opraw, ushort_t* __restrict__ opxb,
    float* __restrict__ mlbuf, int zoff)
{
  const int qt = blockIdx.x;
  const int h = blockIdx.y;
  const int z = blockIdx.z + zoff;
  const int t = threadIdx.x;
  const int lane = t & 63;
  const int w = t >> 6;
  const int ql = lane & 31;
  const int hi = lane >> 5;

  __shared__ __attribute__((aligned(16))) ushort_t Ks[64 * 128];
  __shared__ __attribute__((aligned(16))) ushort_t Vs[128 * 64];

  const int q0 = qt * 64 + w * 32;
  const size_t kbase = (size_t)h * S_LEN * 128;
  const size_t vbase = (size_t)h * 128 * S_LEN;

  bf16x8 qf[8];
#pragma unroll
  for (int s = 0; s < 8; ++s)
    qf[s] = *(const bf16x8*)(Qh + ((size_t)h * S_LEN + q0 + ql) * 128 + 16 * s + 8 * hi);

  AttnState st_;
#pragma unroll
  for (int dt = 0; dt < 4; ++dt)
#pragma unroll
    for (int r = 0; r < 16; ++r) st_.oacc[dt][r] = 0.f;
  st_.mrun = -1e30f; st_.lrun = 0.f;

  const int kvbeg = z * (S_LEN / KVSPLIT);
  const int kvend = kvbeg + S_LEN / KVSPLIT;
  for (int kv0 = kvbeg; kv0 < kvend; kv0 += 64) {
    __syncthreads();
    stage_kv(Kh + kbase + (size_t)kv0 * 128, VT + vbase + kv0, Ks, Vs, t);
    __syncthreads();
    attn_tile(Ks, Vs, qf, st_, ql, hi);
  }
  attn_epilogue(st_, z, h * S_LEN + q0 + ql, hi, opraw, opxb, mlbuf);
}

// ------------------------- V1: 2-phase double-buffered prefetch pipeline
// Raw s_barrier (no fence -> no compiler vmcnt(0) drain); counted vmcnt(16)
// keeps next tile's 16 global_load_lds in flight across the barrier (T3/T4).
__global__ void __launch_bounds__(128) attn32p(
    const ushort_t* __restrict__ Qh, const ushort_t* __restrict__ Kh,
    const ushort_t* __restrict__ VT,
    ushort_t* __restrict__ opraw, ushort_t* __restrict__ opxb,
    float* __restrict__ mlbuf, int zoff)
{
  const int qt = blockIdx.x;
  const int h = blockIdx.y;
  const int z = blockIdx.z + zoff;
  const int t = threadIdx.x;
  const int lane = t & 63;
  const int w = t >> 6;
  const int ql = lane & 31;
  const int hi = lane >> 5;

  __shared__ __attribute__((aligned(16))) ushort_t Ks[2][64 * 128];
  __shared__ __attribute__((aligned(16))) ushort_t Vs[2][128 * 64];

  const int q0 = qt * 64 + w * 32;
  const size_t kbase = (size_t)h * S_LEN * 128;
  const size_t vbase = (size_t)h * 128 * S_LEN;

  bf16x8 qf[8];
#pragma unroll
  for (int s = 0; s < 8; ++s)
    qf[s] = *(const bf16x8*)(Qh + ((size_t)h * S_LEN + q0 + ql) * 128 + 16 * s + 8 * hi);

  AttnState st_;
#pragma unroll
  for (int dt = 0; dt < 4; ++dt)
#pragma unroll
    for (int r = 0; r < 16; ++r) st_.oacc[dt][r] = 0.f;
  st_.mrun = -1e30f; st_.lrun = 0.f;

  const int kvbeg = z * (S_LEN / KVSPLIT);
  const int NT = (S_LEN / KVSPLIT) / 64;   // 16 tiles

  stage_kv(Kh + kbase + (size_t)kvbeg * 128, VT + vbase + kvbeg, Ks[0], Vs[0], t);

  for (int it = 0; it < NT; ++it) {
    const int cur = it & 1;
    if (it + 1 < NT) {
      const int kvn = kvbeg + (it + 1) * 64;
      stage_kv(Kh + kbase + (size_t)kvn * 128, VT + vbase + kvn, Ks[cur ^ 1], Vs[cur ^ 1], t);
      asm volatile("s_waitcnt vmcnt(16)" ::: "memory");   // cur's 16 done; next's in flight
    } else {
      asm volatile("s_waitcnt vmcnt(0)" ::: "memory");
    }
    __builtin_amdgcn_sched_barrier(0);
    __builtin_amdgcn_s_barrier();           // raw: no implicit vmcnt(0) drain
    __builtin_amdgcn_sched_barrier(0);
    attn_tile(Ks[cur], Vs[cur], qf, st_, ql, hi);
    __builtin_amdgcn_s_barrier();           // all waves done reading cur before restage
  }
  attn_epilogue(st_, z, h * S_LEN + q0 + ql, hi, opraw, opxb, mlbuf);
}

// ------------------------------------------------ combine KV-split partials
__global__ void __launch_bounds__(256) attn_combine(
    const ushort_t* __restrict__ opraw, const ushort_t* __restrict__ opxb,
    const float* __restrict__ mlbuf, ushort_t* __restrict__ hb)
{
  int gidx = blockIdx.x * 256 + threadIdx.x;
  int r = gidx >> 4;
  int c = gidx & 15;

  float m[KVSPLIT], l[KVSPLIT];
#pragma unroll
  for (int zz = 0; zz < KVSPLIT; ++zz) {
    m[zz] = mlbuf[2 * ((size_t)zz * ROWS + r)];
    l[zz] = mlbuf[2 * ((size_t)zz * ROWS + r) + 1];
  }
  float M = fmaxf(fmaxf(m[0], m[1]), fmaxf(m[2], m[3]));
  float wsum = 0.f, wz[KVSPLIT];
#pragma unroll
  for (int zz = 0; zz < KVSPLIT; ++zz) {
    wz[zz] = l[zz] * exp2f(m[zz] - M);
    wsum += wz[zz];
  }
  float invw = 1.f / wsum;

  float o[8];
#pragma unroll
  for (int j = 0; j < 8; ++j) o[j] = 0.f;
#pragma unroll
  for (int zz = 0; zz < KVSPLIT; ++zz) {
    const ushort_t* Op = (zz < 3) ? (opraw + (size_t)zz * OPSPLIT_ELEMS) : opxb;
    bf16x8 v = *(const bf16x8*)(Op + (size_t)r * 128 + c * 8);
#pragma unroll
    for (int j = 0; j < 8; ++j) o[j] += wz[zz] * bf2f((ushort_t)v[j]);
  }
  uint4 u;
  u.x = cvtpk(o[0] * invw, o[1] * invw);
  u.y = cvtpk(o[2] * invw, o[3] * invw);
  u.z = cvtpk(o[4] * invw, o[5] * invw);
  u.w = cvtpk(o[6] * invw, o[7] * invw);
  int q = r & (S_LEN - 1), h = r >> 12;
  *(uint4*)(hb + (size_t)q * DIM + h * 128 + c * 8) = u;
}

// ------------------------------------------------------------------ launch
extern "C" void kernel_launch(void* const* d_in, const int* in_sizes, int n_in,
                              void* d_out, int out_size, void* d_ws, size_t ws_size,
                              hipStream_t stream) {
  const float* x    = (const float*)d_in[0];
  const float* fcos = (const float*)d_in[1];
  const float* fsin = (const float*)d_in[2];
  const float* Wq   = (const float*)d_in[3];
  const float* bq   = (const float*)d_in[4];
  const float* Wk   = (const float*)d_in[5];
  const float* bk   = (const float*)d_in[6];
  const float* Wv   = (const float*)d_in[7];
  const float* bv   = (const float*)d_in[8];
  const float* Wo   = (const float*)d_in[9];
  const float* bo   = (const float*)d_in[10];
  const float* gq   = (const float*)d_in[11];
  const float* gk   = (const float*)d_in[12];

  char* ws = (char*)d_ws;
  ushort_t* xb  = (ushort_t*)(ws);              // [4096][1536]; reused as O-partial z=3
  ushort_t* wb  = (ushort_t*)(ws + 12582912);   // [4][1536][1536]
  ushort_t* raw = (ushort_t*)(ws + 31457280);   // [3][4096][1536]; reused as O-partial z=0..2
  ushort_t* Qh  = (ushort_t*)(ws + 69206016);   // [12][4096][128]
  ushort_t* Kh  = (ushort_t*)(ws + 81788928);
  ushort_t* Vh  = (ushort_t*)(ws + 94371840);   // reused as (m,l) buffer after transpose_v
  ushort_t* VT  = (ushort_t*)(ws + 106954752);  // [12][128][4096]
  ushort_t* hb  = (ushort_t*)(ws + 119537664);  // [4096][1536]

  cvt_bf16<<<2048, 256, 0, stream>>>(x,  xb,             6291456 / 4);
  cvt_bf16<<<2048, 256, 0, stream>>>(Wq, wb + 0 * 2359296, 2359296 / 4);
  cvt_bf16<<<2048, 256, 0, stream>>>(Wk, wb + 1 * 2359296, 2359296 / 4);
  cvt_bf16<<<2048, 256, 0, stream>>>(Wv, wb + 2 * 2359296, 2359296 / 4);
  cvt_bf16<<<2048, 256, 0, stream>>>(Wo, wb + 3 * 2359296, 2359296 / 4);

  gemm_bt<0><<<dim3(12, 32, 3), 256, 0, stream>>>(xb, wb, bq, bk, bv,
                                                  (void*)raw, 4096, 1536, 1536);
  epi_qkv<<<4096, 256, 0, stream>>>(raw, gq, gk, fcos, fsin, Qh, Kh, Vh);
  transpose_v<<<dim3(64, 2, 12), 256, 0, stream>>>(Vh, VT);

  // within-probe A/B: V0 (serial) on splits 0-1, V1 (pipelined) on splits 2-3
  attn32 <<<dim3(64, 12, 2), 128, 0, stream>>>(Qh, Kh, VT, raw, xb, (float*)Vh, 0);
  attn32p<<<dim3(64, 12, 2), 128, 0, stream>>>(Qh, Kh, VT, raw, xb, (float*)Vh, 2);

  attn_combine<<<3072, 256, 0, stream>>>(raw, xb, (const float*)Vh, hb);
  gemm_bt<1><<<dim3(12, 32, 1), 256, 0, stream>>>(hb, wb + 3 * 2359296, bo, bo, bo,
                                                  (void*)d_out, 4096, 1536, 1536);
}

// Round 8
// 531.184 us; speedup vs baseline: 1.0091x; 1.0091x over previous
//
#include <hip/hip_runtime.h>

typedef unsigned short ushort_t;
typedef short bf16x8 __attribute__((ext_vector_type(8)));
typedef float f32x4 __attribute__((ext_vector_type(4)));
typedef float f32x16 __attribute__((ext_vector_type(16)));

#define S_LEN 4096
#define DIM   1536
#define NH    12
#define HD    128
#define KVSPLIT 4
#define ROWS (NH * S_LEN)
#define OPSPLIT_ELEMS ((size_t)ROWS * HD)

__device__ __forceinline__ float bf2f(ushort_t h) {
  union { unsigned u; float f; } v; v.u = ((unsigned)h) << 16; return v.f;
}
__device__ __forceinline__ ushort_t f2bf(float f) {
  union { float f; unsigned u; } v; v.f = f;
  return (ushort_t)((v.u + 0x7FFFu + ((v.u >> 16) & 1u)) >> 16);
}
__device__ __forceinline__ unsigned cvtpk(float lo, float hi_) {
  unsigned r; asm("v_cvt_pk_bf16_f32 %0, %1, %2" : "=v"(r) : "v"(lo), "v"(hi_)); return r;
}

// async global->LDS, 16B per lane; LDS dest must be uniform base + lane*16
#define GLD16(gp, lp) __builtin_amdgcn_global_load_lds( \
    (const __attribute__((address_space(1))) unsigned int*)(gp), \
    (__attribute__((address_space(3))) unsigned int*)(lp), 16, 0, 0)

// ---------------------------------------------------------------- convert
__global__ void __launch_bounds__(256) cvt_bf16(const float* __restrict__ in,
                                                ushort_t* __restrict__ out, int n4) {
  int i = blockIdx.x * 256 + threadIdx.x;
  int stride = gridDim.x * 256;
  for (; i < n4; i += stride) {
    float4 v = ((const float4*)in)[i];
    ushort4 o;
    o.x = f2bf(v.x); o.y = f2bf(v.y); o.z = f2bf(v.z); o.w = f2bf(v.w);
    ((ushort4*)out)[i] = o;
  }
}

// ------------------------------------------------- GEMM: C = A * W^T + bias
template <int F32OUT>
__global__ void __launch_bounds__(256) gemm_bt(
    const ushort_t* __restrict__ A, const ushort_t* __restrict__ Wbase,
    const float* __restrict__ b0, const float* __restrict__ b1, const float* __restrict__ b2,
    void* __restrict__ Cbase_v, int M, int N, int K)
{
  const int z = blockIdx.z;
  const ushort_t* W = Wbase + (size_t)z * N * K;
  const float* bias = (z == 0) ? b0 : (z == 1) ? b1 : b2;

  const int n0 = blockIdx.x * 128;
  const int m0 = blockIdx.y * 128;
  const int t = threadIdx.x;
  const int lane = t & 63;
  const int w = t >> 6;
  const int wr = w >> 1, wc = w & 1;
  const int mp = lane & 15, g = lane >> 4;

  __shared__ __attribute__((aligned(16))) ushort_t As[128 * 64];
  __shared__ __attribute__((aligned(16))) ushort_t Bs[128 * 64];

  f32x4 acc[4][4];
  f32x4 zero = {0.f, 0.f, 0.f, 0.f};
#pragma unroll
  for (int i = 0; i < 4; ++i)
#pragma unroll
    for (int j = 0; j < 4; ++j) acc[i][j] = zero;

  for (int kt = 0; kt < K; kt += 64) {
    __syncthreads();
#pragma unroll
    for (int i = 0; i < 4; ++i) {
      int p = i * 256 + t;
      int r = p >> 3, sl = p & 7;
      int sg = sl ^ (r & 7);
      GLD16(A + (size_t)(m0 + r) * K + kt + sg * 8, As + p * 8);
      GLD16(W + (size_t)(n0 + r) * K + kt + sg * 8, Bs + p * 8);
    }
    __syncthreads();
#pragma unroll
    for (int kk = 0; kk < 2; ++kk) {
      bf16x8 af[4], bfr[4];
#pragma unroll
      for (int mi = 0; mi < 4; ++mi) {
        int row = wr * 64 + mi * 16 + mp;
        int ch = (g + 4 * kk) ^ (row & 7);
        af[mi] = *(const bf16x8*)(As + row * 64 + ch * 8);
      }
#pragma unroll
      for (int ni = 0; ni < 4; ++ni) {
        int row = wc * 64 + ni * 16 + mp;
        int ch = (g + 4 * kk) ^ (row & 7);
        bfr[ni] = *(const bf16x8*)(Bs + row * 64 + ch * 8);
      }
#pragma unroll
      for (int mi = 0; mi < 4; ++mi)
#pragma unroll
        for (int ni = 0; ni < 4; ++ni)
          acc[mi][ni] = __builtin_amdgcn_mfma_f32_16x16x32_bf16(af[mi], bfr[ni], acc[mi][ni], 0, 0, 0);
    }
  }
#pragma unroll
  for (int ni = 0; ni < 4; ++ni) {
    int n = n0 + wc * 64 + ni * 16 + mp;
    float bv = bias[n];
#pragma unroll
    for (int mi = 0; mi < 4; ++mi) {
      int mbase = m0 + wr * 64 + mi * 16 + g * 4;
#pragma unroll
      for (int j = 0; j < 4; ++j) {
        if constexpr (F32OUT) {
          ((float*)Cbase_v)[(size_t)z * M * N + (size_t)(mbase + j) * N + n] =
              acc[mi][ni][j] + bv;
        } else {
          ((ushort_t*)Cbase_v)[(size_t)z * M * N + (size_t)(mbase + j) * N + n] =
              f2bf(acc[mi][ni][j] + bv);
        }
      }
    }
  }
}

// ------------------------------------- epilogue: RMSNorm + RoPE + relayout
__global__ void __launch_bounds__(256) epi_qkv(
    const ushort_t* __restrict__ raw,
    const float* __restrict__ gq, const float* __restrict__ gk,
    const float* __restrict__ fcos, const float* __restrict__ fsin,
    ushort_t* __restrict__ Qh, ushort_t* __restrict__ Kh, ushort_t* __restrict__ Vh)
{
  const int s = blockIdx.x;
  const int t = threadIdx.x;
  const ushort_t* rq = raw + (size_t)s * DIM;
  const ushort_t* rk = raw + (size_t)S_LEN * DIM + (size_t)s * DIM;
  const ushort_t* rv = raw + 2 * (size_t)S_LEN * DIM + (size_t)s * DIM;

  float sq = 0.f, sk = 0.f;
#pragma unroll
  for (int i = 0; i < 6; ++i) {
    int e = t + 256 * i;
    float a = bf2f(rq[e]); sq += a * a;
    float b = bf2f(rk[e]); sk += b * b;
  }
  for (int off = 1; off < 64; off <<= 1) {
    sq += __shfl_xor(sq, off, 64);
    sk += __shfl_xor(sk, off, 64);
  }
  __shared__ float red[2][4];
  int w = t >> 6;
  if ((t & 63) == 0) { red[0][w] = sq; red[1][w] = sk; }
  __syncthreads();
  sq = red[0][0] + red[0][1] + red[0][2] + red[0][3];
  sk = red[1][0] + red[1][1] + red[1][2] + red[1][3];
  float invq = rsqrtf(sq * (1.f / 1536.f) + 1e-6f);
  float invk = rsqrtf(sk * (1.f / 1536.f) + 1e-6f);

  const float qscale = 0.12752004708465604f;  // log2(e)/sqrt(128)
#pragma unroll
  for (int i = 0; i < 3; ++i) {
    int p = t + 256 * i;
    int hh = p >> 6, d = p & 63;
    int e1 = hh * 128 + d, e2 = e1 + 64;
    float c1 = fcos[s * 128 + d],      s1 = fsin[s * 128 + d];
    float c2 = fcos[s * 128 + d + 64], s2 = fsin[s * 128 + d + 64];
    float q1 = bf2f(rq[e1]) * invq * gq[e1];
    float q2 = bf2f(rq[e2]) * invq * gq[e2];
    float k1 = bf2f(rk[e1]) * invk * gk[e1];
    float k2 = bf2f(rk[e2]) * invk * gk[e2];
    size_t ob = ((size_t)hh * S_LEN + s) * 128;
    Qh[ob + d]      = f2bf((q1 * c1 - q2 * s1) * qscale);
    Qh[ob + d + 64] = f2bf((q2 * c2 + q1 * s2) * qscale);
    Kh[ob + d]      = f2bf(k1 * c1 - k2 * s1);
    Kh[ob + d + 64] = f2bf(k2 * c2 + k1 * s2);
  }
#pragma unroll
  for (int i = 0; i < 6; ++i) {
    int e = t + 256 * i;
    int hh = e >> 7, d = e & 127;
    Vh[((size_t)hh * S_LEN + s) * 128 + d] = rv[e];
  }
}

// ----------------------------------------------- V -> V^T per head (tiled)
__global__ void __launch_bounds__(256) transpose_v(const ushort_t* __restrict__ Vh,
                                                   ushort_t* __restrict__ VT) {
  const int st = blockIdx.x * 64;
  const int dt = blockIdx.y * 64;
  const int h = blockIdx.z;
  __shared__ ushort_t tile[64][65];
  const int t = threadIdx.x;
#pragma unroll
  for (int i = 0; i < 2; ++i) {
    int p = i * 256 + t;
    int r = p >> 3, c = (p & 7) * 8;
    bf16x8 v = *(const bf16x8*)(Vh + ((size_t)h * S_LEN + st + r) * 128 + dt + c);
#pragma unroll
    for (int j = 0; j < 8; ++j) tile[r][c + j] = ((ushort_t*)&v)[j];
  }
  __syncthreads();
#pragma unroll
  for (int i = 0; i < 2; ++i) {
    int p = i * 256 + t;
    int r = p >> 3, c = (p & 7) * 8;
    ushort_t tmp[8];
#pragma unroll
    for (int j = 0; j < 8; ++j) tmp[j] = tile[c + j][r];
    *(bf16x8*)(VT + ((size_t)h * 128 + dt + r) * S_LEN + st + c) = *(bf16x8*)tmp;
  }
}

// ------------------------------ stage one 64-KV tile with 256 threads
__device__ __forceinline__ void stage_kv256(const ushort_t* __restrict__ Kg,
                                            const ushort_t* __restrict__ Vg,
                                            ushort_t* KsB, ushort_t* VsB, int t) {
#pragma unroll
  for (int i = 0; i < 4; ++i) {        // K tile: 64 rows x 16 chunks
    int p = i * 256 + t;
    int r = p >> 4, sl = p & 15;
    int sg = sl ^ (r & 7);
    GLD16(Kg + (size_t)r * 128 + sg * 8, KsB + p * 8);
  }
#pragma unroll
  for (int i = 0; i < 4; ++i) {        // V^T tile: 128 rows x 8 chunks
    int p = i * 256 + t;
    int r = p >> 3, sl = p & 7;
    int sg = sl ^ (r & 7);
    GLD16(Vg + (size_t)r * S_LEN + sg * 8, VsB + p * 8);
  }
}

struct AttnState {
  f32x16 oacc[4];
  float mrun, lrun;
};

// compute one 64-KV tile from LDS buffers (swapped QK^T + in-reg softmax + PV)
__device__ __forceinline__ void attn_tile(const ushort_t* KsB, const ushort_t* VsB,
                                          const bf16x8* qf, AttnState& st_,
                                          int ql, int hi) {
  f32x16 sa0, sa1;
#pragma unroll
  for (int r = 0; r < 16; ++r) { sa0[r] = 0.f; sa1[r] = 0.f; }
  __builtin_amdgcn_s_setprio(1);
#pragma unroll
  for (int s = 0; s < 8; ++s) {
    int ck = (2 * s + hi) ^ (ql & 7);
    bf16x8 k0 = *(const bf16x8*)(KsB + ql * 128 + ck * 8);
    bf16x8 k1 = *(const bf16x8*)(KsB + (32 + ql) * 128 + ck * 8);
    sa0 = __builtin_amdgcn_mfma_f32_32x32x16_bf16(k0, qf[s], sa0, 0, 0, 0);
    sa1 = __builtin_amdgcn_mfma_f32_32x32x16_bf16(k1, qf[s], sa1, 0, 0, 0);
  }
  __builtin_amdgcn_s_setprio(0);

  float mt[8];
#pragma unroll
  for (int r = 0; r < 8; ++r)
    mt[r] = fmaxf(fmaxf(sa0[r], sa0[r + 8]), fmaxf(sa1[r], sa1[r + 8]));
#pragma unroll
  for (int off = 4; off > 0; off >>= 1)
#pragma unroll
    for (int r = 0; r < 8; ++r)
      if (r < off) mt[r] = fmaxf(mt[r], mt[r + off]);
  float mx = fmaxf(mt[0], __shfl_xor(mt[0], 32));

  if (__any(mx - st_.mrun > 11.0f)) {
    float nm = fmaxf(st_.mrun, mx);
    float sc = exp2f(st_.mrun - nm);
    st_.mrun = nm;
    st_.lrun *= sc;
#pragma unroll
    for (int dt = 0; dt < 4; ++dt)
#pragma unroll
      for (int r = 0; r < 16; ++r) st_.oacc[dt][r] *= sc;
  }

  float rt[8];
#pragma unroll
  for (int r = 0; r < 16; ++r) {
    sa0[r] = exp2f(sa0[r] - st_.mrun);
    sa1[r] = exp2f(sa1[r] - st_.mrun);
  }
#pragma unroll
  for (int r = 0; r < 8; ++r) rt[r] = (sa0[r] + sa0[r + 8]) + (sa1[r] + sa1[r + 8]);
#pragma unroll
  for (int off = 4; off > 0; off >>= 1)
#pragma unroll
    for (int r = 0; r < 8; ++r)
      if (r < off) rt[r] += rt[r + off];
  st_.lrun += rt[0] + __shfl_xor(rt[0], 32);

  unsigned pw0[8], pw1[8];
#pragma unroll
  for (int a = 0; a < 4; ++a) {
    pw0[2 * a]     = cvtpk(sa0[4 * a], sa0[4 * a + 1]);
    pw0[2 * a + 1] = cvtpk(sa0[4 * a + 2], sa0[4 * a + 3]);
    pw1[2 * a]     = cvtpk(sa1[4 * a], sa1[4 * a + 1]);
    pw1[2 * a + 1] = cvtpk(sa1[4 * a + 2], sa1[4 * a + 3]);
  }

#pragma unroll
  for (int sx = 0; sx < 2; ++sx) {
#pragma unroll
    for (int ks = 0; ks < 2; ++ks) {
      unsigned q0w0 = sx ? pw1[4 * ks + 0] : pw0[4 * ks + 0];
      unsigned q0w1 = sx ? pw1[4 * ks + 1] : pw0[4 * ks + 1];
      unsigned q1w0 = sx ? pw1[4 * ks + 2] : pw0[4 * ks + 2];
      unsigned q1w1 = sx ? pw1[4 * ks + 3] : pw0[4 * ks + 3];
      unsigned sw0 = hi ? q0w0 : q1w0;
      unsigned sw1 = hi ? q0w1 : q1w1;
      unsigned rv0 = (unsigned)__shfl_xor((int)sw0, 32);
      unsigned rv1 = (unsigned)__shfl_xor((int)sw1, 32);
      union { unsigned u[4]; bf16x8 v; } fw;
      fw.u[0] = hi ? rv0 : q0w0;
      fw.u[1] = hi ? rv1 : q0w1;
      fw.u[2] = hi ? q1w0 : rv0;
      fw.u[3] = hi ? q1w1 : rv1;
      __builtin_amdgcn_s_setprio(1);
#pragma unroll
      for (int dt = 0; dt < 4; ++dt) {
        int d = 32 * dt + ql;
        int cv = (4 * sx + 2 * ks + hi) ^ (ql & 7);
        bf16x8 va = *(const bf16x8*)(VsB + d * 64 + cv * 8);
        st_.oacc[dt] = __builtin_amdgcn_mfma_f32_32x32x16_bf16(va, fw.v, st_.oacc[dt], 0, 0, 0);
      }
      __builtin_amdgcn_s_setprio(0);
    }
  }
}

__device__ __forceinline__ void attn_epilogue(AttnState& st_, int z, int row, int hi,
                                              ushort_t* __restrict__ opraw,
                                              ushort_t* __restrict__ opxb,
                                              float* __restrict__ mlbuf) {
  ushort_t* Op = (z < 3) ? (opraw + (size_t)z * OPSPLIT_ELEMS) : opxb;
  float inv = 1.f / st_.lrun;
#pragma unroll
  for (int dt = 0; dt < 4; ++dt) {
#pragma unroll
    for (int c = 0; c < 4; ++c) {
      float f0 = st_.oacc[dt][4 * c + 0] * inv, f1 = st_.oacc[dt][4 * c + 1] * inv;
      float f2 = st_.oacc[dt][4 * c + 2] * inv, f3 = st_.oacc[dt][4 * c + 3] * inv;
      uint2 u;
      u.x = cvtpk(f0, f1);
      u.y = cvtpk(f2, f3);
      *(uint2*)(Op + (size_t)row * 128 + 32 * dt + 8 * c + 4 * hi) = u;
    }
  }
  if (hi == 0) {
    mlbuf[2 * ((size_t)z * ROWS + row)]     = st_.mrun;
    mlbuf[2 * ((size_t)z * ROWS + row) + 1] = st_.lrun;
  }
}

// ---------------- attention: 4 waves x 32 q-rows share one 32KB K/V tile.
// Bijective XCD swizzle (1536 wgs = 8 x 192): each XCD gets a contiguous
// 192-block run = 6 heads x 32 q-tiles x 1 split -> per-XCD KV set 3MB < L2.
__global__ void __launch_bounds__(256) attn32(
    const ushort_t* __restrict__ Qh, const ushort_t* __restrict__ Kh,
    const ushort_t* __restrict__ VT,
    ushort_t* __restrict__ opraw, ushort_t* __restrict__ opxb,
    float* __restrict__ mlbuf)
{
  int lid = blockIdx.x + 32 * (blockIdx.y + 12 * blockIdx.z);
  int nid = (lid & 7) * 192 + (lid >> 3);
  const int qt = nid & 31;
  const int h = (nid >> 5) % NH;
  const int z = nid / (32 * NH);

  const int t = threadIdx.x;
  const int lane = t & 63;
  const int w = t >> 6;           // 0..3
  const int ql = lane & 31;
  const int hi = lane >> 5;

  __shared__ __attribute__((aligned(16))) ushort_t Ks[64 * 128];
  __shared__ __attribute__((aligned(16))) ushort_t Vs[128 * 64];

  const int q0 = qt * 128 + w * 32;
  const size_t kbase = (size_t)h * S_LEN * 128;
  const size_t vbase = (size_t)h * 128 * S_LEN;

  bf16x8 qf[8];
#pragma unroll
  for (int s = 0; s < 8; ++s)
    qf[s] = *(const bf16x8*)(Qh + ((size_t)h * S_LEN + q0 + ql) * 128 + 16 * s + 8 * hi);

  AttnState st_;
#pragma unroll
  for (int dt = 0; dt < 4; ++dt)
#pragma unroll
    for (int r = 0; r < 16; ++r) st_.oacc[dt][r] = 0.f;
  st_.mrun = -1e30f; st_.lrun = 0.f;

  const int kvbeg = z * (S_LEN / KVSPLIT);
  const int kvend = kvbeg + S_LEN / KVSPLIT;
  for (int kv0 = kvbeg; kv0 < kvend; kv0 += 64) {
    __syncthreads();
    stage_kv256(Kh + kbase + (size_t)kv0 * 128, VT + vbase + kv0, Ks, Vs, t);
    __syncthreads();
    attn_tile(Ks, Vs, qf, st_, ql, hi);
  }
  attn_epilogue(st_, z, h * S_LEN + q0 + ql, hi, opraw, opxb, mlbuf);
}

// ------------------------------------------------ combine KV-split partials
__global__ void __launch_bounds__(256) attn_combine(
    const ushort_t* __restrict__ opraw, const ushort_t* __restrict__ opxb,
    const float* __restrict__ mlbuf, ushort_t* __restrict__ hb)
{
  int gidx = blockIdx.x * 256 + threadIdx.x;
  int r = gidx >> 4;
  int c = gidx & 15;

  float m[KVSPLIT], l[KVSPLIT];
#pragma unroll
  for (int zz = 0; zz < KVSPLIT; ++zz) {
    m[zz] = mlbuf[2 * ((size_t)zz * ROWS + r)];
    l[zz] = mlbuf[2 * ((size_t)zz * ROWS + r) + 1];
  }
  float M = fmaxf(fmaxf(m[0], m[1]), fmaxf(m[2], m[3]));
  float wsum = 0.f, wz[KVSPLIT];
#pragma unroll
  for (int zz = 0; zz < KVSPLIT; ++zz) {
    wz[zz] = l[zz] * exp2f(m[zz] - M);
    wsum += wz[zz];
  }
  float invw = 1.f / wsum;

  float o[8];
#pragma unroll
  for (int j = 0; j < 8; ++j) o[j] = 0.f;
#pragma unroll
  for (int zz = 0; zz < KVSPLIT; ++zz) {
    const ushort_t* Op = (zz < 3) ? (opraw + (size_t)zz * OPSPLIT_ELEMS) : opxb;
    bf16x8 v = *(const bf16x8*)(Op + (size_t)r * 128 + c * 8);
#pragma unroll
    for (int j = 0; j < 8; ++j) o[j] += wz[zz] * bf2f((ushort_t)v[j]);
  }
  uint4 u;
  u.x = cvtpk(o[0] * invw, o[1] * invw);
  u.y = cvtpk(o[2] * invw, o[3] * invw);
  u.z = cvtpk(o[4] * invw, o[5] * invw);
  u.w = cvtpk(o[6] * invw, o[7] * invw);
  int q = r & (S_LEN - 1), h = r >> 12;
  *(uint4*)(hb + (size_t)q * DIM + h * 128 + c * 8) = u;
}

// ------------------------------------------------------------------ launch
extern "C" void kernel_launch(void* const* d_in, const int* in_sizes, int n_in,
                              void* d_out, int out_size, void* d_ws, size_t ws_size,
                              hipStream_t stream) {
  const float* x    = (const float*)d_in[0];
  const float* fcos = (const float*)d_in[1];
  const float* fsin = (const float*)d_in[2];
  const float* Wq   = (const float*)d_in[3];
  const float* bq   = (const float*)d_in[4];
  const float* Wk   = (const float*)d_in[5];
  const float* bk   = (const float*)d_in[6];
  const float* Wv   = (const float*)d_in[7];
  const float* bv   = (const float*)d_in[8];
  const float* Wo   = (const float*)d_in[9];
  const float* bo   = (const float*)d_in[10];
  const float* gq   = (const float*)d_in[11];
  const float* gk   = (const float*)d_in[12];

  char* ws = (char*)d_ws;
  ushort_t* xb  = (ushort_t*)(ws);              // [4096][1536]; reused as O-partial z=3
  ushort_t* wb  = (ushort_t*)(ws + 12582912);   // [4][1536][1536]
  ushort_t* raw = (ushort_t*)(ws + 31457280);   // [3][4096][1536]; reused as O-partial z=0..2
  ushort_t* Qh  = (ushort_t*)(ws + 69206016);   // [12][4096][128]
  ushort_t* Kh  = (ushort_t*)(ws + 81788928);
  ushort_t* Vh  = (ushort_t*)(ws + 94371840);   // reused as (m,l) buffer after transpose_v
  ushort_t* VT  = (ushort_t*)(ws + 106954752);  // [12][128][4096]
  ushort_t* hb  = (ushort_t*)(ws + 119537664);  // [4096][1536]

  cvt_bf16<<<2048, 256, 0, stream>>>(x,  xb,             6291456 / 4);
  cvt_bf16<<<2048, 256, 0, stream>>>(Wq, wb + 0 * 2359296, 2359296 / 4);
  cvt_bf16<<<2048, 256, 0, stream>>>(Wk, wb + 1 * 2359296, 2359296 / 4);
  cvt_bf16<<<2048, 256, 0, stream>>>(Wv, wb + 2 * 2359296, 2359296 / 4);
  cvt_bf16<<<2048, 256, 0, stream>>>(Wo, wb + 3 * 2359296, 2359296 / 4);

  gemm_bt<0><<<dim3(12, 32, 3), 256, 0, stream>>>(xb, wb, bq, bk, bv,
                                                  (void*)raw, 4096, 1536, 1536);
  epi_qkv<<<4096, 256, 0, stream>>>(raw, gq, gk, fcos, fsin, Qh, Kh, Vh);
  transpose_v<<<dim3(64, 2, 12), 256, 0, stream>>>(Vh, VT);

  attn32<<<dim3(32, 12, KVSPLIT), 256, 0, stream>>>(Qh, Kh, VT, raw, xb, (float*)Vh);

  attn_combine<<<3072, 256, 0, stream>>>(raw, xb, (const float*)Vh, hb);
  gemm_bt<1><<<dim3(12, 32, 1), 256, 0, stream>>>(hb, wb + 3 * 2359296, bo, bo, bo,
                                                  (void*)d_out, 4096, 1536, 1536);
}